// Round 5
// baseline (301.986 us; speedup 1.0000x reference)
//
#include <hip/hip_runtime.h>

// ---------------------------------------------------------------------------
// WindowedMSA: B=2, H=W=256, C=96, win=16, heads=4, hd=24
// Fully fused mega-kernel: x -> qkv (MFMA, z in registers) -> windowed
// attention + LePE -> out-projection. Q/K/VT never touch HBM.
// grid 1024 = (window, token-half), 256 threads, target 3 blocks/CU.
// Round-5 fix: zero-init all LDS pads that MFMA operands can read
// (uninitialized LDS NaN x 0 = NaN poisoned round 4).
// ---------------------------------------------------------------------------

typedef __attribute__((ext_vector_type(8))) short bf16x8;
typedef __attribute__((ext_vector_type(4))) float f32x4;

#define MFMA(a, b, c) __builtin_amdgcn_mfma_f32_16x16x32_bf16(a, b, c, 0, 0, 0)

#if __has_builtin(__builtin_amdgcn_exp2f)
#define EXP2F(x) __builtin_amdgcn_exp2f(x)
#else
#define EXP2F(x) exp2f(x)
#endif

#define SCALE2 (0.20412414523193154f * 1.4426950408889634f)

// ws layout (bytes) — weights only
#define OFF_WT   0u           // ushort[288*96]  qkv_w^T bf16 (row=out-ch, k-contig)
#define OFF_B2   55296u       // float[288]      qkv bias (q entries pre-scaled)
#define OFF_WTO  56448u       // ushort[96*96 + 128 pad]  out_w^T bf16

__device__ __forceinline__ unsigned short f2bf(float f) {
    union { float f; unsigned int u; } v; v.f = f;
    unsigned int u = v.u;
    return (unsigned short)((u + 0x7FFFu + ((u >> 16) & 1u)) >> 16);
}
__device__ __forceinline__ float bf2f(unsigned short h) {
    union { unsigned int u; float f; } v; v.u = ((unsigned int)h) << 16;
    return v.f;
}
__device__ __forceinline__ unsigned int pk2bf(float a, float b) {
#if __has_builtin(__builtin_amdgcn_cvt_pk_bf16_f32)
    auto p = __builtin_amdgcn_cvt_pk_bf16_f32(a, b);
    union { decltype(p) v; unsigned int u; } cv; cv.v = p;
    return cv.u;
#else
    return (unsigned int)f2bf(a) | ((unsigned int)f2bf(b) << 16);
#endif
}
__device__ __forceinline__ float frcp(float x) {
#if __has_builtin(__builtin_amdgcn_rcpf)
    return __builtin_amdgcn_rcpf(x);
#else
    return 1.0f / x;
#endif
}

// ---------------------------------------------------------------------------
// prep: bf16 transposed weights + scaled bias (+ zeroed wto tail pad)
// ---------------------------------------------------------------------------
__global__ void prep_kernel(const float* __restrict__ qkv_w,
                            const float* __restrict__ qkv_b,
                            const float* __restrict__ out_w,
                            unsigned short* __restrict__ wt,
                            float* __restrict__ b2,
                            unsigned short* __restrict__ wto) {
    const int stride = gridDim.x * 256;
    int i0 = blockIdx.x * 256 + threadIdx.x;
    for (int i = i0; i < 288 * 96; i += stride) {
        const int c = i / 96, k = i % 96;
        float v = qkv_w[k * 288 + c];
        if ((c % 72) < 24) v *= SCALE2;
        wt[i] = f2bf(v);
    }
    for (int i = i0; i < 288; i += stride) {
        float v = qkv_b[i];
        if ((i % 72) < 24) v *= SCALE2;
        b2[i] = v;
    }
    for (int i = i0; i < 96 * 96; i += stride) {
        const int c = i / 96, k = i % 96;
        wto[i] = f2bf(out_w[k * 96 + c]);
    }
    for (int i = i0; i < 128; i += stride) wto[96 * 96 + i] = 0;  // finite tail
}

// ---------------------------------------------------------------------------
// Mega-kernel. Block = (window n, token-half h2). 4 waves.
// ---------------------------------------------------------------------------
__launch_bounds__(256, 3)
__global__ void msa_fused_kernel(const float* __restrict__ x,
                                 const unsigned short* __restrict__ wt,
                                 const float* __restrict__ b2,
                                 const float* __restrict__ pe_w,
                                 const float* __restrict__ pe_b,
                                 const unsigned short* __restrict__ wto,
                                 const float* __restrict__ out_b,
                                 float* __restrict__ out) {
    __shared__ __align__(16) unsigned short sK[256 * 24 + 8];   // 12304 B
    __shared__ __align__(16) unsigned short sQ[128 * 24 + 8];   // 6160 B
    __shared__ __align__(16) unsigned short sVT[32 * 264];      // 16896 B (row24=ones)
    __shared__ __align__(16) unsigned short sP[4 * 32 * 40];    // 10240 B wave-private
    __shared__ __align__(16) float sPW[216];
    __shared__ __align__(16) float sPB[24];

    const int blk = blockIdx.x;
    const int n = blk >> 1, h2 = blk & 1;
    const int tid = threadIdx.x;
    const int w = tid >> 6, l = tid & 63;
    const int lm = l & 15, lq = l >> 4;
    const int bW = n >> 8, hy = (n >> 4) & 15, wx = n & 15;

    // K/V token-tiles: own-half query tiles first, then other half's
    int gtile[4];
    gtile[0] = h2 * 8 + 2 * w; gtile[1] = gtile[0] + 1;
    gtile[2] = (1 - h2) * 8 + 2 * w; gtile[3] = gtile[2] + 1;

    // ---- zero ALL LDS that MFMA operands may read but no one writes ----
    // (uninit LDS can hold bf16 NaN/Inf patterns; NaN*0 = NaN in MFMA)
    if (tid < 8) sK[256 * 24 + tid] = 0;          // sK tail pad (kf lq==3, token 255)
    if (tid < 8) sQ[128 * 24 + tid] = 0;          // sQ tail pad
    for (int i = tid; i < 7 * 132; i += 256)      // sVT rows 25..31 (full 264 cols)
        ((unsigned int*)&sVT[25 * 264])[i] = 0u;

    // ---- z fragments straight from global x (A- and B-operand compatible) ----
    bf16x8 az[4][3];
#pragma unroll
    for (int tt = 0; tt < 4; tt++) {
        const size_t row = (size_t)((bW * 256 + hy * 16 + gtile[tt]) * 256 + wx * 16 + lm);
#pragma unroll
        for (int ks = 0; ks < 3; ks++) {
            const float* p = x + row * 96 + ks * 32 + lq * 8;
            const float4 f0 = *(const float4*)p;
            const float4 f1 = *(const float4*)(p + 4);
            union { bf16x8 v; unsigned int u[4]; } t;
            t.u[0] = pk2bf(f0.x, f0.y); t.u[1] = pk2bf(f0.z, f0.w);
            t.u[2] = pk2bf(f1.x, f1.y); t.u[3] = pk2bf(f1.z, f1.w);
            az[tt][ks] = t.v;
        }
    }

    // ones row of sVT (row 24) — static across heads
    if (tid < 64) {
        ushort4 ones; ones.x = ones.y = ones.z = ones.w = (unsigned short)0x3F80;
        *(ushort4*)&sVT[24 * 264 + tid * 4] = ones;
    }

    f32x4 oacc[2][6];
#pragma unroll
    for (int b = 0; b < 2; b++)
#pragma unroll
        for (int nt = 0; nt < 6; nt++) oacc[b][nt] = (f32x4){0.f, 0.f, 0.f, 0.f};

    unsigned short* Pw = &sP[w * 32 * 40];

    for (int h = 0; h < 4; h++) {
        __syncthreads();   // previous head's readers done (also fences init writes)

        // ---- per-head consts ----
        if (tid < 216) sPW[tid] = pe_w[(tid / 24) * 96 + h * 24 + (tid % 24)];
        if (tid < 24)  sPB[tid] = pe_b[h * 24 + tid];

        // ---- Q for own 32 queries ----
        {
            bf16x8 afQ[2][3];
#pragma unroll
            for (int mt = 0; mt < 2; mt++)
#pragma unroll
                for (int ks = 0; ks < 3; ks++)
                    afQ[mt][ks] = *(const bf16x8*)(wt + (h * 72 + mt * 16 + lm) * 96 + ks * 32 + lq * 8);
#pragma unroll
            for (int tt = 0; tt < 2; tt++) {
#pragma unroll
                for (int mt = 0; mt < 2; mt++) {
                    f32x4 acc = {0.f, 0.f, 0.f, 0.f};
#pragma unroll
                    for (int ks = 0; ks < 3; ks++) acc = MFMA(afQ[mt][ks], az[tt][ks], acc);
                    const int ch0 = mt * 16 + lq * 4;
                    if (ch0 < 24) {
                        const float4 bq = *(const float4*)(b2 + h * 72 + ch0);
                        uint2 pk;
                        pk.x = pk2bf(acc[0] + bq.x, acc[1] + bq.y);
                        pk.y = pk2bf(acc[2] + bq.z, acc[3] + bq.w);
                        *(uint2*)&sQ[(w * 32 + tt * 16 + lm) * 24 + ch0] = pk;
                    }
                }
            }
        }
        // ---- K for 4 token-tiles (full window across waves) ----
        {
            bf16x8 afK[2][3];
#pragma unroll
            for (int mt = 0; mt < 2; mt++)
#pragma unroll
                for (int ks = 0; ks < 3; ks++)
                    afK[mt][ks] = *(const bf16x8*)(wt + (h * 72 + 24 + mt * 16 + lm) * 96 + ks * 32 + lq * 8);
#pragma unroll
            for (int tt = 0; tt < 4; tt++) {
#pragma unroll
                for (int mt = 0; mt < 2; mt++) {
                    f32x4 acc = {0.f, 0.f, 0.f, 0.f};
#pragma unroll
                    for (int ks = 0; ks < 3; ks++) acc = MFMA(afK[mt][ks], az[tt][ks], acc);
                    const int ch0 = mt * 16 + lq * 4;
                    if (ch0 < 24) {
                        const float4 bk = *(const float4*)(b2 + h * 72 + 24 + ch0);
                        uint2 pk;
                        pk.x = pk2bf(acc[0] + bk.x, acc[1] + bk.y);
                        pk.y = pk2bf(acc[2] + bk.z, acc[3] + bk.w);
                        *(uint2*)&sK[(gtile[tt] * 16 + lm) * 24 + ch0] = pk;
                    }
                }
            }
        }
        // ---- V^T for 4 token-tiles ----
        {
            bf16x8 bv[2][3];
#pragma unroll
            for (int vt = 0; vt < 2; vt++)
#pragma unroll
                for (int ks = 0; ks < 3; ks++) {
                    int r = h * 72 + 48 + vt * 16 + lm;
                    r = r > 287 ? 287 : r;   // clamp; garbage column predicated off
                    bv[vt][ks] = *(const bf16x8*)(wt + r * 96 + ks * 32 + lq * 8);
                }
#pragma unroll
            for (int tt = 0; tt < 4; tt++) {
#pragma unroll
                for (int vt = 0; vt < 2; vt++) {
                    f32x4 acc = {0.f, 0.f, 0.f, 0.f};
#pragma unroll
                    for (int ks = 0; ks < 3; ks++) acc = MFMA(az[tt][ks], bv[vt][ks], acc);
                    const int ch = vt * 16 + lm;
                    if (ch < 24) {
                        const float bb = b2[h * 72 + 48 + ch];
                        uint2 pk;
                        pk.x = pk2bf(acc[0] + bb, acc[1] + bb);
                        pk.y = pk2bf(acc[2] + bb, acc[3] + bb);
                        *(uint2*)&sVT[ch * 264 + gtile[tt] * 16 + lq * 4] = pk;
                    }
                }
            }
        }
        __syncthreads();

        // ---- attention: 32 queries x 256 keys ----
        bf16x8 qf[2];
#pragma unroll
        for (int b = 0; b < 2; b++) {
            bf16x8 qv = *(const bf16x8*)&sQ[(w * 32 + b * 16 + lm) * 24 + lq * 8];
            if (lq == 3) qv = (bf16x8)(short)0;
            qf[b] = qv;
        }
        f32x4 oa[2][2];
#pragma unroll
        for (int b = 0; b < 2; b++)
#pragma unroll
            for (int c = 0; c < 2; c++) oa[b][c] = (f32x4){0.f, 0.f, 0.f, 0.f};

        for (int kc = 0; kc < 8; kc++) {
#pragma unroll
            for (int a = 0; a < 2; a++) {
                const bf16x8 kf = *(const bf16x8*)&sK[(kc * 32 + a * 16 + lm) * 24 + lq * 8];
                f32x4 s[2];
#pragma unroll
                for (int b = 0; b < 2; b++)
                    s[b] = MFMA(kf, qf[b], ((f32x4){0.f, 0.f, 0.f, 0.f}));
#pragma unroll
                for (int b = 0; b < 2; b++) {
                    uint2 pk;
                    pk.x = pk2bf(EXP2F(s[b][0]), EXP2F(s[b][1]));
                    pk.y = pk2bf(EXP2F(s[b][2]), EXP2F(s[b][3]));
                    *(uint2*)&Pw[(b * 16 + lm) * 40 + a * 16 + lq * 4] = pk;
                }
            }
            bf16x8 vb[2];
#pragma unroll
            for (int c = 0; c < 2; c++)
                vb[c] = *(const bf16x8*)&sVT[(c * 16 + lm) * 264 + kc * 32 + lq * 8];
#pragma unroll
            for (int b = 0; b < 2; b++) {
                const bf16x8 pa = *(const bf16x8*)&Pw[(b * 16 + lm) * 40 + lq * 8];
#pragma unroll
                for (int c = 0; c < 2; c++) oa[b][c] = MFMA(pa, vb[c], oa[b][c]);
            }
        }

        // ---- epilogue: denominators, LePE, O -> wave-private LDS ----
        if (l < 32) {  // zero O k-pad cols 24..31 (after last P read)
            uint4 zz = {0u, 0u, 0u, 0u};
            *(uint4*)&Pw[l * 40 + 24] = zz;
        }
        float w9[2][9], pb2[2];
#pragma unroll
        for (int c = 0; c < 2; c++) {
            const int ch = c * 16 + lm;
            if (ch < 24) {
#pragma unroll
                for (int ta = 0; ta < 9; ta++) w9[c][ta] = sPW[ta * 24 + ch];
                pb2[c] = sPB[ch];
            }
        }
#pragma unroll
        for (int b = 0; b < 2; b++) {
            float rinv[4];
#pragma unroll
            for (int r = 0; r < 4; r++)
                rinv[r] = frcp(__shfl(oa[b][1][r], (l & 48) | 8, 64));
            const int y = h2 * 8 + 2 * w + b;   // tile row in window
            const int x0 = lq * 4;
#pragma unroll
            for (int c = 0; c < 2; c++) {
                const int ch = c * 16 + lm;
                if (ch < 24) {
                    float lep[4] = {pb2[c], pb2[c], pb2[c], pb2[c]};
                    const unsigned short* vbase = &sVT[ch * 264];
#pragma unroll
                    for (int dy = -1; dy <= 1; dy++) {
                        const int ny = y + dy;
                        if ((unsigned)ny > 15u) continue;
                        const unsigned short* vrow = vbase + ny * 16;
                        const float wl = w9[c][(dy + 1) * 3 + 0];
                        const float wm = w9[c][(dy + 1) * 3 + 1];
                        const float wr = w9[c][(dy + 1) * 3 + 2];
#pragma unroll
                        for (int d = -1; d <= 4; d++) {
                            const int xx = x0 + d;
                            if ((unsigned)xx > 15u) continue;
                            const float v = bf2f(vrow[xx]);
                            if (d - 1 >= 0 && d - 1 <= 3) lep[d - 1] = fmaf(v, wr, lep[d - 1]);
                            if (d >= 0 && d <= 3)         lep[d]     = fmaf(v, wm, lep[d]);
                            if (d + 1 <= 3)               lep[d + 1] = fmaf(v, wl, lep[d + 1]);
                        }
                    }
#pragma unroll
                    for (int r = 0; r < 4; r++) {
                        const float val = oa[b][c][r] * rinv[r] + lep[r];
                        Pw[(b * 16 + lq * 4 + r) * 40 + ch] = f2bf(val);
                    }
                }
            }
        }

        // ---- partial out-projection (wave-private O in LDS, in-order DS) ----
        bf16x8 aO[2];
#pragma unroll
        for (int b = 0; b < 2; b++)
            aO[b] = *(const bf16x8*)&Pw[(b * 16 + lm) * 40 + lq * 8];
#pragma unroll
        for (int nt = 0; nt < 6; nt++) {
            const bf16x8 bwf = *(const bf16x8*)(wto + (nt * 16 + lm) * 96 + h * 24 + lq * 8);
#pragma unroll
            for (int b = 0; b < 2; b++) oacc[b][nt] = MFMA(aO[b], bwf, oacc[b][nt]);
        }
    }

    // ---- final store with reverse window partition ----
#pragma unroll
    for (int nt = 0; nt < 6; nt++) {
        const float bias = out_b[nt * 16 + lm];
#pragma unroll
        for (int b = 0; b < 2; b++) {
#pragma unroll
            for (int r = 0; r < 4; r++) {
                const int t = h2 * 128 + w * 32 + b * 16 + lq * 4 + r;
                const size_t grow =
                    (size_t)((bW * 256 + hy * 16 + (t >> 4)) * 256 + wx * 16 + (t & 15));
                out[grow * 96 + nt * 16 + lm] = oacc[b][nt][r] + bias;
            }
        }
    }
}

extern "C" void kernel_launch(void* const* d_in, const int* in_sizes, int n_in,
                              void* d_out, int out_size, void* d_ws, size_t ws_size,
                              hipStream_t stream) {
    const float* x     = (const float*)d_in[0];
    const float* qkv_w = (const float*)d_in[1];
    const float* qkv_b = (const float*)d_in[2];
    const float* pe_w  = (const float*)d_in[3];
    const float* pe_b  = (const float*)d_in[4];
    const float* out_w = (const float*)d_in[5];
    const float* out_b = (const float*)d_in[6];
    float* out = (float*)d_out;

    char* ws = (char*)d_ws;
    unsigned short* wt  = (unsigned short*)(ws + OFF_WT);
    float*          b2  = (float*)(ws + OFF_B2);
    unsigned short* wto = (unsigned short*)(ws + OFF_WTO);

    prep_kernel<<<72, 256, 0, stream>>>(qkv_w, qkv_b, out_w, wt, b2, wto);
    msa_fused_kernel<<<1024, 256, 0, stream>>>(x, wt, b2, pe_w, pe_b, wto, out_b, out);
}